// Round 16
// baseline (378.395 us; speedup 1.0000x reference)
//
#include <hip/hip_runtime.h>
#include <math.h>

#define NQ    12
#define DIM   4096        // 2^NQ
#define K_EXT 8192        // [hi | lo] extended row
#define KSL   1024        // K per slice (8 slices)
#define NSAMP 2048
#define NLAY  3
#define NT2   16          // 2048/128 tiles per dimension
#define NTRI2 136         // NT2*(NT2+1)/2 triangular tiles
#define NSLICE 8
#define BK    64
#define LDK   72          // LDS row stride (ushort); 144 B, 16B-aligned rows

typedef __attribute__((ext_vector_type(8)))  short bf16x8;   // 8 bf16 = 4 VGPRs
typedef __attribute__((ext_vector_type(16))) float floatx16; // MFMA 32x32 acc

__device__ __forceinline__ unsigned short f32_to_bf16(float x) {
    unsigned u = __builtin_bit_cast(unsigned, x);
    u += 0x7FFFu + ((u >> 16) & 1u);            // round-to-nearest-even
    return (unsigned short)(u >> 16);
}
__device__ __forceinline__ float bf16_to_f32(unsigned short h) {
    unsigned u = (unsigned)h << 16;
    return __builtin_bit_cast(float, u);
}

__device__ __forceinline__ void tri_decode(int bid, int& bi, int& bj) {
    int i = (int)((33.0 - sqrt(33.0*33.0 - 8.0*(double)bid)) * 0.5);
    int start = i*(33-i)/2;
    while (bid < start)               { --i; start = i*(33-i)/2; }
    while (bid >= start + (NT2 - i))  { start += NT2 - i; ++i; }
    bi = i; bj = i + (bid - start);
}

// ---------------------------------------------------------------------------
// Kernel 1: one sample per TWO waves (v[32]/lane).
// K-PERMUTED bit map: i = (w*64+lane)*32 + r  (qubits 0-4 = r bits,
// qubits 5-10 = lane bits, qubit 11 = w).  Fixed k-permutation is
// Gram-invariant; RYs within a layer commute so order is free.
// CZ ring parity for this map: P4(r) ^ (r4&l0) ^ P5(lane) ^ (l5&w) ^ (w&r0).
// Payoff: each lane owns 32 CONTIGUOUS k -> stores become 8 uint4
// (was 64 scalar ushort stores).
// Qubit-5/6 butterflies via DPP quad_perm (VALU pipe, xor1=0xB1, xor2=0x4E).
// ---------------------------------------------------------------------------
__global__ __launch_bounds__(256) void sim_kernel(const float* __restrict__ data,
                                                  const float* __restrict__ params,
                                                  unsigned short* __restrict__ pe)
{
    __shared__ float CS[2*36], SN[2*36];
    __shared__ float ex[2][128*33];     // +1 pad -> 2-way banks (free)
    const int tid  = threadIdx.x;
    const int wave = tid >> 6, lane = tid & 63;
    const int sidx = wave >> 1;         // sample within block
    const int w    = wave & 1;          // qubit-11 bit
    const int smp  = blockIdx.x * 2 + sidx;

    if (w == 0 && lane < NLAY*NQ) {
        const int q = lane % NQ;
        const float th = 0.5f * (params[lane] + data[smp*NQ + q]);
        CS[sidx*36 + lane] = cosf(th);
        SN[sidx*36 + lane] = sinf(th);
    }
    __syncthreads();

    float v[32];
    #pragma unroll
    for (int r = 0; r < 32; ++r) v[r] = 0.f;
    if (w == 0 && lane == 0) v[0] = 1.f;

    // CZ lane-side sign bases for the new map
    const int P5 = __popc(lane & (lane >> 1) & 0x1F) & 1;   // edges q5..q10
    const int l0 = lane & 1, l5 = (lane >> 5) & 1;
    const int base = P5 ^ (l5 & w);
    const float fA0 = base             ? -1.f : 1.f;  // r4=0, r0=0
    const float fA1 = (base ^ w)       ? -1.f : 1.f;  // r4=0, r0=1
    const float fB0 = (base ^ l0)      ? -1.f : 1.f;  // r4=1, r0=0
    const float fB1 = (base ^ l0 ^ w)  ? -1.f : 1.f;  // r4=1, r0=1

    float*       exw = &ex[sidx][(w*64       + lane)*33];
    const float* exp_ = &ex[sidx][((1-w)*64  + lane)*33];

    #pragma unroll 1
    for (int l = 0; l < NLAY; ++l) {
        const float* cs = &CS[sidx*36 + l*NQ];
        const float* sn = &SN[sidx*36 + l*NQ];
        // qubits 0-4: register butterflies (bits 0..4 of r)
        #pragma unroll
        for (int b = 0; b < 5; ++b) {
            const float c = cs[b], s = sn[b];
            const int M = 1 << b;
            #pragma unroll
            for (int r = 0; r < 32; ++r) {
                if (!(r & M)) {
                    const float a0 = v[r], a1 = v[r | M];
                    v[r]     = c * a0 - s * a1;
                    v[r | M] = s * a0 + c * a1;
                }
            }
        }
        // qubits 5,6: DPP quad_perm butterflies (VALU pipe)
        {
            const float c0 = cs[5], s0 = sn[5];
            const float t0 = (lane & 1) ? s0 : -s0;
            #pragma unroll
            for (int r = 0; r < 32; ++r) {
                const int iv = __builtin_bit_cast(int, v[r]);
                const int pv = __builtin_amdgcn_update_dpp(0, iv, 0xB1, 0xF, 0xF, true);
                v[r] = c0 * v[r] + t0 * __builtin_bit_cast(float, pv);
            }
            const float c1 = cs[6], s1 = sn[6];
            const float t1 = (lane & 2) ? s1 : -s1;
            #pragma unroll
            for (int r = 0; r < 32; ++r) {
                const int iv = __builtin_bit_cast(int, v[r]);
                const int pv = __builtin_amdgcn_update_dpp(0, iv, 0x4E, 0xF, 0xF, true);
                v[r] = c1 * v[r] + t1 * __builtin_bit_cast(float, pv);
            }
        }
        // qubits 7-10: lane shfl butterflies (lane bits 2..5)
        #pragma unroll 1
        for (int q = 7; q < 11; ++q) {
            const float c = cs[q], s = sn[q];
            const int   lb = q - 5;
            const float t = ((lane >> lb) & 1) ? s : -s;
            const int   m = 1 << lb;
            #pragma unroll
            for (int r = 0; r < 32; ++r) {
                const float p = __shfl_xor(v[r], m, 64);
                v[r] = c * v[r] + t * p;
            }
        }
        // qubit 11: cross-wave butterfly via LDS exchange
        {
            const float c = cs[11], s = sn[11];
            const float t = w ? s : -s;
            __syncthreads();
            #pragma unroll
            for (int r = 0; r < 32; ++r) exw[r] = v[r];
            __syncthreads();
            #pragma unroll
            for (int r = 0; r < 32; ++r) v[r] = c * v[r] + t * exp_[r];
        }
        // CZ ring sign
        #pragma unroll
        for (int r = 0; r < 32; ++r) {
            const int P4 = __popc(r & (r >> 1) & 0xF) & 1;
            const int r0 = r & 1, r4 = (r >> 4) & 1;
            float f = r4 ? (r0 ? fB1 : fB0) : (r0 ? fA1 : fA0);
            if (P4) f = -f;
            v[r] *= f;
        }
    }

    // vector stores: 32 contiguous ushorts each for hi and lo
    unsigned short* outh = pe + (size_t)smp * K_EXT + (w*64 + lane)*32;
    unsigned short* outl = outh + DIM;
    #pragma unroll
    for (int c = 0; c < 4; ++c) {
        uint4 H, L;
        {
            const float x0 = v[c*8+0], x1 = v[c*8+1];
            const unsigned short h0 = f32_to_bf16(x0), h1 = f32_to_bf16(x1);
            H.x = (unsigned)h0 | ((unsigned)h1 << 16);
            L.x = (unsigned)f32_to_bf16(x0 - bf16_to_f32(h0)) |
                  ((unsigned)f32_to_bf16(x1 - bf16_to_f32(h1)) << 16);
        }
        {
            const float x0 = v[c*8+2], x1 = v[c*8+3];
            const unsigned short h0 = f32_to_bf16(x0), h1 = f32_to_bf16(x1);
            H.y = (unsigned)h0 | ((unsigned)h1 << 16);
            L.y = (unsigned)f32_to_bf16(x0 - bf16_to_f32(h0)) |
                  ((unsigned)f32_to_bf16(x1 - bf16_to_f32(h1)) << 16);
        }
        {
            const float x0 = v[c*8+4], x1 = v[c*8+5];
            const unsigned short h0 = f32_to_bf16(x0), h1 = f32_to_bf16(x1);
            H.z = (unsigned)h0 | ((unsigned)h1 << 16);
            L.z = (unsigned)f32_to_bf16(x0 - bf16_to_f32(h0)) |
                  ((unsigned)f32_to_bf16(x1 - bf16_to_f32(h1)) << 16);
        }
        {
            const float x0 = v[c*8+6], x1 = v[c*8+7];
            const unsigned short h0 = f32_to_bf16(x0), h1 = f32_to_bf16(x1);
            H.w = (unsigned)h0 | ((unsigned)h1 << 16);
            L.w = (unsigned)f32_to_bf16(x0 - bf16_to_f32(h0)) |
                  ((unsigned)f32_to_bf16(x1 - bf16_to_f32(h1)) << 16);
        }
        *(uint4*)&outh[c*8] = H;
        *(uint4*)&outl[c*8] = L;
    }
}

// ---------------------------------------------------------------------------
// Kernel 2: partial Gram + FUSED last-arriver reduction.
// 1088 blocks = 136 tiles x 8 K-slices, tile-major decode (slice = bid&7 ->
// one K-slice per XCD = 4 MiB = its whole L2; R15 verified FETCH 173->24 MB).
// After writing its Gp slice, each block increments cnt[tile]; the 8th
// arrival re-reads the 8 (L2/LLC-warm) slices and does square/weight/reduce
// in place — eliminates the separate gram_reduce dispatch.
// All registers NAMED (indexed register arrays spill on this compiler).
// ---------------------------------------------------------------------------
__global__ __launch_bounds__(256, 2) void gram_partial(const unsigned short* __restrict__ pe,
                                                       float* __restrict__ Gp,
                                                       int* __restrict__ cnt,
                                                       const int* __restrict__ labels,
                                                       double* __restrict__ part1,
                                                       double* __restrict__ part2)
{
    __shared__ __align__(16) unsigned short As[128*LDK];   // 18.4 KiB
    __shared__ __align__(16) unsigned short Bs[128*LDK];   // 18.4 KiB
    __shared__ float la[128], lb[128];
    __shared__ double red[256];
    __shared__ int lastFlag;

    const int tid   = threadIdx.x;
    const int tile  = blockIdx.x >> 3;     // bi-major tile walk per XCD
    const int slice = blockIdx.x & 7;      // one K-slice per XCD (bid % 8)
    int bi, bj; tri_decode(tile, bi, bj);
    const int k0 = slice * KSL;

    const int wave = tid >> 6, lane = tid & 63;
    const int qr = (wave >> 1) * 64;   // quadrant row offset
    const int qc = (wave &  1) * 64;   // quadrant col offset
    const int mrow = lane & 31;
    const int kgrp = (lane >> 5) * 8;  // A/B layout: lane holds M[lane&31][(lane>>5)*8+j]

    floatx16 c00, c01, c10, c11;
    #pragma unroll
    for (int i = 0; i < 16; ++i) { c00[i]=0.f; c01[i]=0.f; c10[i]=0.f; c11[i]=0.f; }

    const int r = tid >> 1;
    const int h = (tid & 1) * 32;      // ushort offset (64 B)
    const unsigned short* gA = pe + ((size_t)bi*128 + r) * K_EXT + k0 + h;
    const unsigned short* gB = pe + ((size_t)bj*128 + r) * K_EXT + k0 + h;
    unsigned short* sA = &As[r*LDK + h];
    unsigned short* sB = &Bs[r*LDK + h];

    uint4 pa0 = *(const uint4*)(gA +  0), pa1 = *(const uint4*)(gA +  8);
    uint4 pa2 = *(const uint4*)(gA + 16), pa3 = *(const uint4*)(gA + 24);
    uint4 pb0 = *(const uint4*)(gB +  0), pb1 = *(const uint4*)(gB +  8);
    uint4 pb2 = *(const uint4*)(gB + 16), pb3 = *(const uint4*)(gB + 24);

    for (int kk = 0; kk < KSL; kk += BK) {
        __syncthreads();                       // prev readers done
        *(uint4*)(sA +  0) = pa0; *(uint4*)(sA +  8) = pa1;
        *(uint4*)(sA + 16) = pa2; *(uint4*)(sA + 24) = pa3;
        *(uint4*)(sB +  0) = pb0; *(uint4*)(sB +  8) = pb1;
        *(uint4*)(sB + 16) = pb2; *(uint4*)(sB + 24) = pb3;
        __syncthreads();
        if (kk + BK < KSL) {                   // prefetch next stage
            pa0 = *(const uint4*)(gA + kk + BK +  0); pa1 = *(const uint4*)(gA + kk + BK +  8);
            pa2 = *(const uint4*)(gA + kk + BK + 16); pa3 = *(const uint4*)(gA + kk + BK + 24);
            pb0 = *(const uint4*)(gB + kk + BK +  0); pb1 = *(const uint4*)(gB + kk + BK +  8);
            pb2 = *(const uint4*)(gB + kk + BK + 16); pb3 = *(const uint4*)(gB + kk + BK + 24);
        }
        #pragma unroll
        for (int ks = 0; ks < 4; ++ks) {
            const int ro = ks*16 + kgrp;
            const bf16x8 a0 = *(const bf16x8*)&As[(qr +      mrow)*LDK + ro];
            const bf16x8 a1 = *(const bf16x8*)&As[(qr + 32 + mrow)*LDK + ro];
            const bf16x8 b0 = *(const bf16x8*)&Bs[(qc +      mrow)*LDK + ro];
            const bf16x8 b1 = *(const bf16x8*)&Bs[(qc + 32 + mrow)*LDK + ro];
            c00 = __builtin_amdgcn_mfma_f32_32x32x16_bf16(a0, b0, c00, 0, 0, 0);
            c01 = __builtin_amdgcn_mfma_f32_32x32x16_bf16(a0, b1, c01, 0, 0, 0);
            c10 = __builtin_amdgcn_mfma_f32_32x32x16_bf16(a1, b0, c10, 0, 0, 0);
            c11 = __builtin_amdgcn_mfma_f32_32x32x16_bf16(a1, b1, c11, 0, 0, 0);
        }
    }

    // Write partial G quadrants.  C/D layout (m74/m101).
    float* Gt = Gp + ((size_t)slice * NTRI2 + tile) * 16384;
    const int crow = (lane >> 5) * 4;
    const int ccol = lane & 31;
    #pragma unroll
    for (int rr = 0; rr < 16; ++rr) {
        const int rl = (rr & 3) + 8*(rr >> 2) + crow;    // 0..31
        const int r0 = qr + rl,  r1 = qr + 32 + rl;
        const int cA = qc + ccol, cB = qc + 32 + ccol;
        Gt[r0*128 + cA] = c00[rr];
        Gt[r0*128 + cB] = c01[rr];
        Gt[r1*128 + cA] = c10[rr];
        Gt[r1*128 + cB] = c11[rr];
    }

    // ---- last-arriver reduction ----
    __threadfence();                           // release Gt writes
    if (tid == 0) lastFlag = (atomicAdd(&cnt[tile], 1) == NSLICE - 1);
    __syncthreads();
    if (!lastFlag) return;
    __threadfence();                           // acquire other slices' writes

    if (tid < 128) la[tid]       = 2.0f*(float)labels[bi*128 + tid]       - 1.0f;
    else           lb[tid - 128] = 2.0f*(float)labels[bj*128 + tid - 128] - 1.0f;
    __syncthreads();

    const size_t stride = (size_t)NTRI2 * 16384;
    const float* g0 = Gp + (size_t)tile * 16384;
    double s1 = 0.0, s2 = 0.0;
    #pragma unroll 2
    for (int u = 0; u < 64; ++u) {
        const int e = u*256 + tid;
        float g = 0.f;
        #pragma unroll
        for (int s = 0; s < NSLICE; ++s) g += g0[e + (size_t)s*stride];
        const int row = e >> 7, col = e & 127;
        const float wgt = (bi < bj) ? 2.0f : ((row < col) ? 2.0f : ((row == col) ? 1.0f : 0.0f));
        const float g2 = g * g;
        s1 += (double)(wgt * la[row] * lb[col] * g2);
        const double d = (double)g2;
        s2 += (double)wgt * d * d;
    }

    red[tid] = s1; __syncthreads();
    for (int off = 128; off; off >>= 1) { if (tid < off) red[tid] += red[tid+off]; __syncthreads(); }
    if (tid == 0) part1[tile] = red[0];
    __syncthreads();
    red[tid] = s2; __syncthreads();
    for (int off = 128; off; off >>= 1) { if (tid < off) red[tid] += red[tid+off]; __syncthreads(); }
    if (tid == 0) part2[tile] = red[0];
}

// ---------------------------------------------------------------------------
// Kernel 3: reduce 136 partial slots -> scalar f32.
// square_sum_l = N^2 exactly, so out = s1 / (N * sqrt(s2)).
// ---------------------------------------------------------------------------
__global__ __launch_bounds__(256) void finalize_kernel(const double* __restrict__ part1,
                                                       const double* __restrict__ part2,
                                                       float* __restrict__ out)
{
    __shared__ double r1[256], r2[256];
    const int tid = threadIdx.x;
    double a = 0.0, b = 0.0;
    if (tid < NTRI2) { a = part1[tid]; b = part2[tid]; }
    r1[tid] = a; r2[tid] = b; __syncthreads();
    for (int off = 128; off; off >>= 1) {
        if (tid < off) { r1[tid] += r1[tid+off]; r2[tid] += r2[tid+off]; }
        __syncthreads();
    }
    if (tid == 0) out[0] = (float)(r1[0] / (sqrt(r2[0]) * (double)NSAMP));
}

// ---------------------------------------------------------------------------
extern "C" void kernel_launch(void* const* d_in, const int* in_sizes, int n_in,
                              void* d_out, int out_size, void* d_ws, size_t ws_size,
                              hipStream_t stream)
{
    const float* data   = (const float*)d_in[0]; // (2048,12) f32
    const int*   labels = (const int*)d_in[1];   // (2048,)   i32
    const float* params = (const float*)d_in[2]; // (3,12)    f32

    double* part1 = (double*)d_ws;                                    // 256 doubles
    double* part2 = part1 + 256;                                      // 256 doubles
    int*    cnt   = (int*)(part2 + 256);                              // 256 ints
    unsigned short* psi_ext = (unsigned short*)((char*)d_ws + 16384); // 32 MiB
    float* Gp = (float*)((char*)d_ws + 16384 + (size_t)NSAMP*K_EXT*2);// 8x136x16384 f32 = 71.3 MiB

    hipMemsetAsync(cnt, 0, NTRI2 * sizeof(int), stream);
    sim_kernel<<<NSAMP/2, 256, 0, stream>>>(data, params, psi_ext);
    gram_partial<<<NTRI2*NSLICE, 256, 0, stream>>>(psi_ext, Gp, cnt, labels, part1, part2);
    finalize_kernel<<<1, 256, 0, stream>>>(part1, part2, (float*)d_out);
}

// Round 17
// 155.521 us; speedup vs baseline: 2.4331x; 2.4331x over previous
//
#include <hip/hip_runtime.h>
#include <math.h>

#define NQ    12
#define DIM   4096        // 2^NQ
#define K_EXT 8192        // [hi | lo] extended row
#define KSL   1024        // K per slice (8 slices)
#define NSAMP 2048
#define NLAY  3
#define NT2   16          // 2048/128 tiles per dimension
#define NTRI2 136         // NT2*(NT2+1)/2 triangular tiles
#define NSLICE 8
#define BK    64
#define LDK   72          // LDS row stride (ushort); 144 B, 16B-aligned rows

typedef __attribute__((ext_vector_type(8)))  short bf16x8;   // 8 bf16 = 4 VGPRs
typedef __attribute__((ext_vector_type(16))) float floatx16; // MFMA 32x32 acc

__device__ __forceinline__ unsigned short f32_to_bf16(float x) {
    unsigned u = __builtin_bit_cast(unsigned, x);
    u += 0x7FFFu + ((u >> 16) & 1u);            // round-to-nearest-even
    return (unsigned short)(u >> 16);
}
__device__ __forceinline__ float bf16_to_f32(unsigned short h) {
    unsigned u = (unsigned)h << 16;
    return __builtin_bit_cast(float, u);
}

__device__ __forceinline__ void tri_decode(int bid, int& bi, int& bj) {
    int i = (int)((33.0 - sqrt(33.0*33.0 - 8.0*(double)bid)) * 0.5);
    int start = i*(33-i)/2;
    while (bid < start)               { --i; start = i*(33-i)/2; }
    while (bid >= start + (NT2 - i))  { start += NT2 - i; ++i; }
    bi = i; bj = i + (bid - start);
}

// ---------------------------------------------------------------------------
// Kernel 1 (kept from R16 — correctness proven; speed now measured in
// isolation): one sample per TWO waves (v[32]/lane).
// K-PERMUTED bit map: i = (w*64+lane)*32 + r  (qubits 0-4 = r bits,
// qubits 5-10 = lane bits, qubit 11 = w).  Fixed k-permutation is
// Gram-invariant; RYs within a layer commute so order is free.
// CZ parity: P4(r) ^ (r4&l0) ^ P5(lane) ^ (l5&w) ^ (w&r0).
// Each lane owns 32 CONTIGUOUS k -> 8 uint4 stores (was 64 scalar).
// Qubit-5/6 butterflies via DPP quad_perm (VALU pipe, 0xB1 / 0x4E).
// ---------------------------------------------------------------------------
__global__ __launch_bounds__(256) void sim_kernel(const float* __restrict__ data,
                                                  const float* __restrict__ params,
                                                  unsigned short* __restrict__ pe)
{
    __shared__ float CS[2*36], SN[2*36];
    __shared__ float ex[2][128*33];     // +1 pad -> 2-way banks (free)
    const int tid  = threadIdx.x;
    const int wave = tid >> 6, lane = tid & 63;
    const int sidx = wave >> 1;         // sample within block
    const int w    = wave & 1;          // qubit-11 bit
    const int smp  = blockIdx.x * 2 + sidx;

    if (w == 0 && lane < NLAY*NQ) {
        const int q = lane % NQ;
        const float th = 0.5f * (params[lane] + data[smp*NQ + q]);
        CS[sidx*36 + lane] = cosf(th);
        SN[sidx*36 + lane] = sinf(th);
    }
    __syncthreads();

    float v[32];
    #pragma unroll
    for (int r = 0; r < 32; ++r) v[r] = 0.f;
    if (w == 0 && lane == 0) v[0] = 1.f;

    const int P5 = __popc(lane & (lane >> 1) & 0x1F) & 1;   // edges q5..q10
    const int l0 = lane & 1, l5 = (lane >> 5) & 1;
    const int base = P5 ^ (l5 & w);
    const float fA0 = base             ? -1.f : 1.f;  // r4=0, r0=0
    const float fA1 = (base ^ w)       ? -1.f : 1.f;  // r4=0, r0=1
    const float fB0 = (base ^ l0)      ? -1.f : 1.f;  // r4=1, r0=0
    const float fB1 = (base ^ l0 ^ w)  ? -1.f : 1.f;  // r4=1, r0=1

    float*       exw = &ex[sidx][(w*64       + lane)*33];
    const float* exp_ = &ex[sidx][((1-w)*64  + lane)*33];

    #pragma unroll 1
    for (int l = 0; l < NLAY; ++l) {
        const float* cs = &CS[sidx*36 + l*NQ];
        const float* sn = &SN[sidx*36 + l*NQ];
        // qubits 0-4: register butterflies
        #pragma unroll
        for (int b = 0; b < 5; ++b) {
            const float c = cs[b], s = sn[b];
            const int M = 1 << b;
            #pragma unroll
            for (int r = 0; r < 32; ++r) {
                if (!(r & M)) {
                    const float a0 = v[r], a1 = v[r | M];
                    v[r]     = c * a0 - s * a1;
                    v[r | M] = s * a0 + c * a1;
                }
            }
        }
        // qubits 5,6: DPP quad_perm butterflies (VALU pipe)
        {
            const float c0 = cs[5], s0 = sn[5];
            const float t0 = (lane & 1) ? s0 : -s0;
            #pragma unroll
            for (int r = 0; r < 32; ++r) {
                const int iv = __builtin_bit_cast(int, v[r]);
                const int pv = __builtin_amdgcn_update_dpp(0, iv, 0xB1, 0xF, 0xF, true);
                v[r] = c0 * v[r] + t0 * __builtin_bit_cast(float, pv);
            }
            const float c1 = cs[6], s1 = sn[6];
            const float t1 = (lane & 2) ? s1 : -s1;
            #pragma unroll
            for (int r = 0; r < 32; ++r) {
                const int iv = __builtin_bit_cast(int, v[r]);
                const int pv = __builtin_amdgcn_update_dpp(0, iv, 0x4E, 0xF, 0xF, true);
                v[r] = c1 * v[r] + t1 * __builtin_bit_cast(float, pv);
            }
        }
        // qubits 7-10: lane shfl butterflies (lane bits 2..5)
        #pragma unroll 1
        for (int q = 7; q < 11; ++q) {
            const float c = cs[q], s = sn[q];
            const int   lb = q - 5;
            const float t = ((lane >> lb) & 1) ? s : -s;
            const int   m = 1 << lb;
            #pragma unroll
            for (int r = 0; r < 32; ++r) {
                const float p = __shfl_xor(v[r], m, 64);
                v[r] = c * v[r] + t * p;
            }
        }
        // qubit 11: cross-wave butterfly via LDS exchange
        {
            const float c = cs[11], s = sn[11];
            const float t = w ? s : -s;
            __syncthreads();
            #pragma unroll
            for (int r = 0; r < 32; ++r) exw[r] = v[r];
            __syncthreads();
            #pragma unroll
            for (int r = 0; r < 32; ++r) v[r] = c * v[r] + t * exp_[r];
        }
        // CZ ring sign
        #pragma unroll
        for (int r = 0; r < 32; ++r) {
            const int P4 = __popc(r & (r >> 1) & 0xF) & 1;
            const int r0 = r & 1, r4 = (r >> 4) & 1;
            float f = r4 ? (r0 ? fB1 : fB0) : (r0 ? fA1 : fA0);
            if (P4) f = -f;
            v[r] *= f;
        }
    }

    // vector stores: 32 contiguous ushorts each for hi and lo
    unsigned short* outh = pe + (size_t)smp * K_EXT + (w*64 + lane)*32;
    unsigned short* outl = outh + DIM;
    #pragma unroll
    for (int c = 0; c < 4; ++c) {
        uint4 H, L;
        {
            const float x0 = v[c*8+0], x1 = v[c*8+1];
            const unsigned short h0 = f32_to_bf16(x0), h1 = f32_to_bf16(x1);
            H.x = (unsigned)h0 | ((unsigned)h1 << 16);
            L.x = (unsigned)f32_to_bf16(x0 - bf16_to_f32(h0)) |
                  ((unsigned)f32_to_bf16(x1 - bf16_to_f32(h1)) << 16);
        }
        {
            const float x0 = v[c*8+2], x1 = v[c*8+3];
            const unsigned short h0 = f32_to_bf16(x0), h1 = f32_to_bf16(x1);
            H.y = (unsigned)h0 | ((unsigned)h1 << 16);
            L.y = (unsigned)f32_to_bf16(x0 - bf16_to_f32(h0)) |
                  ((unsigned)f32_to_bf16(x1 - bf16_to_f32(h1)) << 16);
        }
        {
            const float x0 = v[c*8+4], x1 = v[c*8+5];
            const unsigned short h0 = f32_to_bf16(x0), h1 = f32_to_bf16(x1);
            H.z = (unsigned)h0 | ((unsigned)h1 << 16);
            L.z = (unsigned)f32_to_bf16(x0 - bf16_to_f32(h0)) |
                  ((unsigned)f32_to_bf16(x1 - bf16_to_f32(h1)) << 16);
        }
        {
            const float x0 = v[c*8+6], x1 = v[c*8+7];
            const unsigned short h0 = f32_to_bf16(x0), h1 = f32_to_bf16(x1);
            H.w = (unsigned)h0 | ((unsigned)h1 << 16);
            L.w = (unsigned)f32_to_bf16(x0 - bf16_to_f32(h0)) |
                  ((unsigned)f32_to_bf16(x1 - bf16_to_f32(h1)) << 16);
        }
        *(uint4*)&outh[c*8] = H;
        *(uint4*)&outl[c*8] = L;
    }
}

// ---------------------------------------------------------------------------
// Kernel 2a (exact R15 revert): partial Gram.  1088 blocks = 136 tiles x 8
// K-slices, TILE-MAJOR decode (slice = bid&7 -> one K-slice per XCD = 4 MiB
// = its whole L2; verified FETCH 173->24 MB).  NO fences/atomics — R16's
// fused last-arriver used __threadfence (buffer_inv: L2 invalidate) per
// block, destroying XCD L2 residency (57 -> 348 us).
// All registers NAMED (indexed register arrays spill on this compiler).
// ---------------------------------------------------------------------------
__global__ __launch_bounds__(256, 2) void gram_partial(const unsigned short* __restrict__ pe,
                                                       float* __restrict__ Gp)
{
    __shared__ __align__(16) unsigned short As[128*LDK];   // 18.4 KiB
    __shared__ __align__(16) unsigned short Bs[128*LDK];   // 18.4 KiB

    const int tid   = threadIdx.x;
    const int tile  = blockIdx.x >> 3;     // bi-major tile walk per XCD
    const int slice = blockIdx.x & 7;      // one K-slice per XCD (bid % 8)
    int bi, bj; tri_decode(tile, bi, bj);
    const int k0 = slice * KSL;

    const int wave = tid >> 6, lane = tid & 63;
    const int qr = (wave >> 1) * 64;   // quadrant row offset
    const int qc = (wave &  1) * 64;   // quadrant col offset
    const int mrow = lane & 31;
    const int kgrp = (lane >> 5) * 8;  // A/B layout: lane holds M[lane&31][(lane>>5)*8+j]

    floatx16 c00, c01, c10, c11;
    #pragma unroll
    for (int i = 0; i < 16; ++i) { c00[i]=0.f; c01[i]=0.f; c10[i]=0.f; c11[i]=0.f; }

    const int r = tid >> 1;
    const int h = (tid & 1) * 32;      // ushort offset (64 B)
    const unsigned short* gA = pe + ((size_t)bi*128 + r) * K_EXT + k0 + h;
    const unsigned short* gB = pe + ((size_t)bj*128 + r) * K_EXT + k0 + h;
    unsigned short* sA = &As[r*LDK + h];
    unsigned short* sB = &Bs[r*LDK + h];

    uint4 pa0 = *(const uint4*)(gA +  0), pa1 = *(const uint4*)(gA +  8);
    uint4 pa2 = *(const uint4*)(gA + 16), pa3 = *(const uint4*)(gA + 24);
    uint4 pb0 = *(const uint4*)(gB +  0), pb1 = *(const uint4*)(gB +  8);
    uint4 pb2 = *(const uint4*)(gB + 16), pb3 = *(const uint4*)(gB + 24);

    for (int kk = 0; kk < KSL; kk += BK) {
        __syncthreads();                       // prev readers done
        *(uint4*)(sA +  0) = pa0; *(uint4*)(sA +  8) = pa1;
        *(uint4*)(sA + 16) = pa2; *(uint4*)(sA + 24) = pa3;
        *(uint4*)(sB +  0) = pb0; *(uint4*)(sB +  8) = pb1;
        *(uint4*)(sB + 16) = pb2; *(uint4*)(sB + 24) = pb3;
        __syncthreads();
        if (kk + BK < KSL) {                   // prefetch next stage
            pa0 = *(const uint4*)(gA + kk + BK +  0); pa1 = *(const uint4*)(gA + kk + BK +  8);
            pa2 = *(const uint4*)(gA + kk + BK + 16); pa3 = *(const uint4*)(gA + kk + BK + 24);
            pb0 = *(const uint4*)(gB + kk + BK +  0); pb1 = *(const uint4*)(gB + kk + BK +  8);
            pb2 = *(const uint4*)(gB + kk + BK + 16); pb3 = *(const uint4*)(gB + kk + BK + 24);
        }
        #pragma unroll
        for (int ks = 0; ks < 4; ++ks) {
            const int ro = ks*16 + kgrp;
            const bf16x8 a0 = *(const bf16x8*)&As[(qr +      mrow)*LDK + ro];
            const bf16x8 a1 = *(const bf16x8*)&As[(qr + 32 + mrow)*LDK + ro];
            const bf16x8 b0 = *(const bf16x8*)&Bs[(qc +      mrow)*LDK + ro];
            const bf16x8 b1 = *(const bf16x8*)&Bs[(qc + 32 + mrow)*LDK + ro];
            c00 = __builtin_amdgcn_mfma_f32_32x32x16_bf16(a0, b0, c00, 0, 0, 0);
            c01 = __builtin_amdgcn_mfma_f32_32x32x16_bf16(a0, b1, c01, 0, 0, 0);
            c10 = __builtin_amdgcn_mfma_f32_32x32x16_bf16(a1, b0, c10, 0, 0, 0);
            c11 = __builtin_amdgcn_mfma_f32_32x32x16_bf16(a1, b1, c11, 0, 0, 0);
        }
    }

    // Write partial G quadrants.  C/D layout (m74/m101).
    float* Gt = Gp + ((size_t)slice * NTRI2 + tile) * 16384;
    const int crow = (lane >> 5) * 4;
    const int ccol = lane & 31;
    #pragma unroll
    for (int rr = 0; rr < 16; ++rr) {
        const int rl = (rr & 3) + 8*(rr >> 2) + crow;    // 0..31
        const int r0 = qr + rl,  r1 = qr + 32 + rl;
        const int cA = qc + ccol, cB = qc + 32 + ccol;
        Gt[r0*128 + cA] = c00[rr];
        Gt[r0*128 + cB] = c01[rr];
        Gt[r1*128 + cA] = c10[rr];
        Gt[r1*128 + cB] = c11[rr];
    }
}

// ---------------------------------------------------------------------------
// Kernel 2b (exact R15 revert): sum the 8 K-slice partials, square, weight,
// reduce.  544 blocks, each a quarter-tile (4096 elements).
// ---------------------------------------------------------------------------
__global__ __launch_bounds__(256) void gram_reduce(const float* __restrict__ Gp,
                                                   const int* __restrict__ labels,
                                                   double* __restrict__ part1,
                                                   double* __restrict__ part2)
{
    __shared__ float la[128], lb[128];
    __shared__ double red[256];
    const int tid  = threadIdx.x;
    const int tile = blockIdx.x >> 2;
    const int quar = blockIdx.x & 3;
    int bi, bj; tri_decode(tile, bi, bj);

    if (tid < 128) la[tid]       = 2.0f*(float)labels[bi*128 + tid]       - 1.0f;
    else           lb[tid - 128] = 2.0f*(float)labels[bj*128 + tid - 128] - 1.0f;
    __syncthreads();

    const size_t stride = (size_t)NTRI2 * 16384;
    const float* g0 = Gp + (size_t)tile * 16384 + quar * 4096;

    double s1 = 0.0, s2 = 0.0;
    #pragma unroll 2
    for (int u = 0; u < 16; ++u) {
        const int e  = u*256 + tid;          // 0..4095 within quarter
        const int ge = quar*4096 + e;
        float g = 0.f;
        #pragma unroll
        for (int s = 0; s < NSLICE; ++s) g += g0[e + (size_t)s*stride];
        const int row = ge >> 7, col = ge & 127;
        const float w = (bi < bj) ? 2.0f : ((row < col) ? 2.0f : ((row == col) ? 1.0f : 0.0f));
        const float g2 = g * g;
        s1 += (double)(w * la[row] * lb[col] * g2);
        const double d = (double)g2;
        s2 += (double)w * d * d;
    }

    red[tid] = s1; __syncthreads();
    for (int off = 128; off; off >>= 1) { if (tid < off) red[tid] += red[tid+off]; __syncthreads(); }
    if (tid == 0) part1[blockIdx.x] = red[0];
    __syncthreads();
    red[tid] = s2; __syncthreads();
    for (int off = 128; off; off >>= 1) { if (tid < off) red[tid] += red[tid+off]; __syncthreads(); }
    if (tid == 0) part2[blockIdx.x] = red[0];
}

// ---------------------------------------------------------------------------
// Kernel 3: reduce 544 partial slots -> scalar f32.
// square_sum_l = N^2 exactly, so out = s1 / (N * sqrt(s2)).
// ---------------------------------------------------------------------------
__global__ __launch_bounds__(256) void finalize_kernel(const double* __restrict__ part1,
                                                       const double* __restrict__ part2,
                                                       float* __restrict__ out)
{
    __shared__ double r1[256], r2[256];
    const int tid = threadIdx.x;
    double a = 0.0, b = 0.0;
    #pragma unroll
    for (int u = 0; u < 3; ++u) {
        const int s = tid + u*256;
        if (s < NTRI2*4) { a += part1[s]; b += part2[s]; }
    }
    r1[tid] = a; r2[tid] = b; __syncthreads();
    for (int off = 128; off; off >>= 1) {
        if (tid < off) { r1[tid] += r1[tid+off]; r2[tid] += r2[tid+off]; }
        __syncthreads();
    }
    if (tid == 0) out[0] = (float)(r1[0] / (sqrt(r2[0]) * (double)NSAMP));
}

// ---------------------------------------------------------------------------
extern "C" void kernel_launch(void* const* d_in, const int* in_sizes, int n_in,
                              void* d_out, int out_size, void* d_ws, size_t ws_size,
                              hipStream_t stream)
{
    const float* data   = (const float*)d_in[0]; // (2048,12) f32
    const int*   labels = (const int*)d_in[1];   // (2048,)   i32
    const float* params = (const float*)d_in[2]; // (3,12)    f32

    double* part1 = (double*)d_ws;                                    // 544 (pad 768) doubles
    double* part2 = part1 + 768;                                      // 544 doubles
    unsigned short* psi_ext = (unsigned short*)((char*)d_ws + 16384); // 32 MiB
    float* Gp = (float*)((char*)d_ws + 16384 + (size_t)NSAMP*K_EXT*2);// 8x136x16384 f32 = 71.3 MiB

    sim_kernel<<<NSAMP/2, 256, 0, stream>>>(data, params, psi_ext);
    gram_partial<<<NTRI2*NSLICE, 256, 0, stream>>>(psi_ext, Gp);
    gram_reduce<<<NTRI2*4, 256, 0, stream>>>(Gp, labels, part1, part2);
    finalize_kernel<<<1, 256, 0, stream>>>(part1, part2, (float*)d_out);
}

// Round 18
// 154.873 us; speedup vs baseline: 2.4433x; 1.0042x over previous
//
#include <hip/hip_runtime.h>
#include <math.h>

#define NQ    12
#define DIM   4096        // 2^NQ
#define K_EXT 8192        // [hi | lo] extended row
#define KSL   1024        // K per slice (8 slices)
#define NSAMP 2048
#define NLAY  3
#define NT2   16          // 2048/128 tiles per dimension
#define NTRI2 136         // NT2*(NT2+1)/2 triangular tiles
#define NSLICE 8
#define BK    64

typedef __attribute__((ext_vector_type(8)))  short bf16x8;   // 8 bf16 = 4 VGPRs
typedef __attribute__((ext_vector_type(16))) float floatx16; // MFMA 32x32 acc

__device__ __forceinline__ unsigned short f32_to_bf16(float x) {
    unsigned u = __builtin_bit_cast(unsigned, x);
    u += 0x7FFFu + ((u >> 16) & 1u);            // round-to-nearest-even
    return (unsigned short)(u >> 16);
}
__device__ __forceinline__ float bf16_to_f32(unsigned short h) {
    unsigned u = (unsigned)h << 16;
    return __builtin_bit_cast(float, u);
}

// async global->LDS, 16 B per lane; LDS dest = wave-uniform base + lane*16
__device__ __forceinline__ void gl_lds16(const unsigned short* g, unsigned short* l) {
    __builtin_amdgcn_global_load_lds(
        (const __attribute__((address_space(1))) unsigned int*)g,
        (__attribute__((address_space(3))) unsigned int*)l,
        16, 0, 0);
}

__device__ __forceinline__ void tri_decode(int bid, int& bi, int& bj) {
    int i = (int)((33.0 - sqrt(33.0*33.0 - 8.0*(double)bid)) * 0.5);
    int start = i*(33-i)/2;
    while (bid < start)               { --i; start = i*(33-i)/2; }
    while (bid >= start + (NT2 - i))  { start += NT2 - i; ++i; }
    bi = i; bj = i + (bid - start);
}

// ---------------------------------------------------------------------------
// Kernel 1: one sample per TWO waves (v[32]/lane).
// K-PERMUTED bit map: i = (w*64+lane)*32 + r.  CZ parity re-derived.
// NEW: psi is stored CHUNK-SWIZZLED in global: within each 128-B (64-k)
// window of sample i, data chunk d lands at position d ^ (i&7).  This makes
// gram's verbatim global_load_lds copy produce a bank-conflict-free LDS
// layout (XOR applied at fragment-read time).  Gram is the only reader.
// ---------------------------------------------------------------------------
__global__ __launch_bounds__(256) void sim_kernel(const float* __restrict__ data,
                                                  const float* __restrict__ params,
                                                  unsigned short* __restrict__ pe)
{
    __shared__ float CS[2*36], SN[2*36];
    __shared__ float ex[2][128*33];     // +1 pad -> 2-way banks (free)
    const int tid  = threadIdx.x;
    const int wave = tid >> 6, lane = tid & 63;
    const int sidx = wave >> 1;         // sample within block
    const int w    = wave & 1;          // qubit-11 bit
    const int smp  = blockIdx.x * 2 + sidx;

    if (w == 0 && lane < NLAY*NQ) {
        const int q = lane % NQ;
        const float th = 0.5f * (params[lane] + data[smp*NQ + q]);
        CS[sidx*36 + lane] = cosf(th);
        SN[sidx*36 + lane] = sinf(th);
    }
    __syncthreads();

    float v[32];
    #pragma unroll
    for (int r = 0; r < 32; ++r) v[r] = 0.f;
    if (w == 0 && lane == 0) v[0] = 1.f;

    const int P5 = __popc(lane & (lane >> 1) & 0x1F) & 1;   // edges q5..q10
    const int l0 = lane & 1, l5 = (lane >> 5) & 1;
    const int base = P5 ^ (l5 & w);
    const float fA0 = base             ? -1.f : 1.f;  // r4=0, r0=0
    const float fA1 = (base ^ w)       ? -1.f : 1.f;  // r4=0, r0=1
    const float fB0 = (base ^ l0)      ? -1.f : 1.f;  // r4=1, r0=0
    const float fB1 = (base ^ l0 ^ w)  ? -1.f : 1.f;  // r4=1, r0=1

    float*       exw = &ex[sidx][(w*64       + lane)*33];
    const float* exp_ = &ex[sidx][((1-w)*64  + lane)*33];

    #pragma unroll 1
    for (int l = 0; l < NLAY; ++l) {
        const float* cs = &CS[sidx*36 + l*NQ];
        const float* sn = &SN[sidx*36 + l*NQ];
        // qubits 0-4: register butterflies
        #pragma unroll
        for (int b = 0; b < 5; ++b) {
            const float c = cs[b], s = sn[b];
            const int M = 1 << b;
            #pragma unroll
            for (int r = 0; r < 32; ++r) {
                if (!(r & M)) {
                    const float a0 = v[r], a1 = v[r | M];
                    v[r]     = c * a0 - s * a1;
                    v[r | M] = s * a0 + c * a1;
                }
            }
        }
        // qubits 5,6: DPP quad_perm butterflies (VALU pipe)
        {
            const float c0 = cs[5], s0 = sn[5];
            const float t0 = (lane & 1) ? s0 : -s0;
            #pragma unroll
            for (int r = 0; r < 32; ++r) {
                const int iv = __builtin_bit_cast(int, v[r]);
                const int pv = __builtin_amdgcn_update_dpp(0, iv, 0xB1, 0xF, 0xF, true);
                v[r] = c0 * v[r] + t0 * __builtin_bit_cast(float, pv);
            }
            const float c1 = cs[6], s1 = sn[6];
            const float t1 = (lane & 2) ? s1 : -s1;
            #pragma unroll
            for (int r = 0; r < 32; ++r) {
                const int iv = __builtin_bit_cast(int, v[r]);
                const int pv = __builtin_amdgcn_update_dpp(0, iv, 0x4E, 0xF, 0xF, true);
                v[r] = c1 * v[r] + t1 * __builtin_bit_cast(float, pv);
            }
        }
        // qubits 7-10: lane shfl butterflies (lane bits 2..5)
        #pragma unroll 1
        for (int q = 7; q < 11; ++q) {
            const float c = cs[q], s = sn[q];
            const int   lb = q - 5;
            const float t = ((lane >> lb) & 1) ? s : -s;
            const int   m = 1 << lb;
            #pragma unroll
            for (int r = 0; r < 32; ++r) {
                const float p = __shfl_xor(v[r], m, 64);
                v[r] = c * v[r] + t * p;
            }
        }
        // qubit 11: cross-wave butterfly via LDS exchange
        {
            const float c = cs[11], s = sn[11];
            const float t = w ? s : -s;
            __syncthreads();
            #pragma unroll
            for (int r = 0; r < 32; ++r) exw[r] = v[r];
            __syncthreads();
            #pragma unroll
            for (int r = 0; r < 32; ++r) v[r] = c * v[r] + t * exp_[r];
        }
        // CZ ring sign
        #pragma unroll
        for (int r = 0; r < 32; ++r) {
            const int P4 = __popc(r & (r >> 1) & 0xF) & 1;
            const int r0 = r & 1, r4 = (r >> 4) & 1;
            float f = r4 ? (r0 ? fB1 : fB0) : (r0 ? fA1 : fA0);
            if (P4) f = -f;
            v[r] *= f;
        }
    }

    // chunk-swizzled vector stores: data chunk gc -> position with low 3
    // bits XORed by (smp&7); hi and lo halves independently (DIM = 512 chunks)
    const int sw = smp & 7;
    const int ell = w*64 + lane;
    unsigned short* outb = pe + (size_t)smp * K_EXT;
    #pragma unroll
    for (int c = 0; c < 4; ++c) {
        uint4 H, L;
        {
            const float x0 = v[c*8+0], x1 = v[c*8+1];
            const unsigned short h0 = f32_to_bf16(x0), h1 = f32_to_bf16(x1);
            H.x = (unsigned)h0 | ((unsigned)h1 << 16);
            L.x = (unsigned)f32_to_bf16(x0 - bf16_to_f32(h0)) |
                  ((unsigned)f32_to_bf16(x1 - bf16_to_f32(h1)) << 16);
        }
        {
            const float x0 = v[c*8+2], x1 = v[c*8+3];
            const unsigned short h0 = f32_to_bf16(x0), h1 = f32_to_bf16(x1);
            H.y = (unsigned)h0 | ((unsigned)h1 << 16);
            L.y = (unsigned)f32_to_bf16(x0 - bf16_to_f32(h0)) |
                  ((unsigned)f32_to_bf16(x1 - bf16_to_f32(h1)) << 16);
        }
        {
            const float x0 = v[c*8+4], x1 = v[c*8+5];
            const unsigned short h0 = f32_to_bf16(x0), h1 = f32_to_bf16(x1);
            H.z = (unsigned)h0 | ((unsigned)h1 << 16);
            L.z = (unsigned)f32_to_bf16(x0 - bf16_to_f32(h0)) |
                  ((unsigned)f32_to_bf16(x1 - bf16_to_f32(h1)) << 16);
        }
        {
            const float x0 = v[c*8+6], x1 = v[c*8+7];
            const unsigned short h0 = f32_to_bf16(x0), h1 = f32_to_bf16(x1);
            H.w = (unsigned)h0 | ((unsigned)h1 << 16);
            L.w = (unsigned)f32_to_bf16(x0 - bf16_to_f32(h0)) |
                  ((unsigned)f32_to_bf16(x1 - bf16_to_f32(h1)) << 16);
        }
        const int gc  = 4*ell + c;
        const int pos = (gc & ~7) | ((gc ^ sw) & 7);
        *(uint4*)&outb[pos*8]       = H;
        *(uint4*)&outb[DIM + pos*8] = L;
    }
}

// ---------------------------------------------------------------------------
// Kernel 2a: partial Gram with ASYNC global_load_lds staging (m97 lever:
// width=16 direct-to-LDS, no VGPR round-trip, no prefetch registers).
// LDS layout packed [row][chunk], LDK=64 — bank conflicts avoided because
// psi is chunk-swizzled in global (pos = chunk ^ (row&7)); fragment reads
// XOR the chunk index.  1088 blocks = 136 tiles x 8 K-slices, tile-major
// decode (one K-slice per XCD = 4 MiB = its L2; FETCH 173->24 MB verified).
// ---------------------------------------------------------------------------
__global__ __launch_bounds__(256) void gram_partial(const unsigned short* __restrict__ pe,
                                                    float* __restrict__ Gp)
{
    __shared__ __align__(16) unsigned short stage[2*128*64];   // A|B, 32 KiB

    unsigned short* As = stage;
    unsigned short* Bs = stage + 128*64;

    const int tid   = threadIdx.x;
    const int tile  = blockIdx.x >> 3;     // bi-major tile walk per XCD
    const int slice = blockIdx.x & 7;      // one K-slice per XCD (bid % 8)
    int bi, bj; tri_decode(tile, bi, bj);
    const int k0 = slice * KSL;

    const int wave = tid >> 6, lane = tid & 63;
    const int qr = (wave >> 1) * 64;   // quadrant row offset
    const int qc = (wave &  1) * 64;   // quadrant col offset
    const int mrow = lane & 31;
    const int chsel = lane >> 5;       // chunk half-select within 16-k group
    const int sw = mrow & 7;           // read-side swizzle key (= row&7)

    floatx16 c00, c01, c10, c11;
    #pragma unroll
    for (int i = 0; i < 16; ++i) { c00[i]=0.f; c01[i]=0.f; c10[i]=0.f; c11[i]=0.f; }

    // async staging assignment: wave -> (matrix, 64-row half); 8 calls/stage,
    // call i covers rows half*64 + i*8 .. +7, lane ℓ -> row +(ℓ>>3), chunk ℓ&7
    const int mat  = wave >> 1;            // 0=A, 1=B
    const int half = wave & 1;
    const unsigned short* gbase = pe
        + ((size_t)((mat ? bj : bi)*128 + half*64 + (lane >> 3))) * K_EXT
        + k0 + (lane & 7)*8;
    unsigned short* lbase = (mat ? Bs : As) + half*64*64;   // ushort units

    for (int kk = 0; kk < KSL; kk += BK) {
        __syncthreads();                       // prev compute done; LDS free
        const unsigned short* g = gbase + kk;
        #pragma unroll
        for (int i = 0; i < 8; ++i)
            gl_lds16(g + (size_t)i*8*K_EXT, lbase + i*512);
        __syncthreads();                       // drains vmcnt -> LDS visible

        #pragma unroll
        for (int ks = 0; ks < 4; ++ks) {
            const int ch = (ks*2 + chsel) ^ sw;            // swizzled chunk
            const bf16x8 a0 = *(const bf16x8*)&As[(qr +      mrow)*64 + ch*8];
            const bf16x8 a1 = *(const bf16x8*)&As[(qr + 32 + mrow)*64 + ch*8];
            const bf16x8 b0 = *(const bf16x8*)&Bs[(qc +      mrow)*64 + ch*8];
            const bf16x8 b1 = *(const bf16x8*)&Bs[(qc + 32 + mrow)*64 + ch*8];
            c00 = __builtin_amdgcn_mfma_f32_32x32x16_bf16(a0, b0, c00, 0, 0, 0);
            c01 = __builtin_amdgcn_mfma_f32_32x32x16_bf16(a0, b1, c01, 0, 0, 0);
            c10 = __builtin_amdgcn_mfma_f32_32x32x16_bf16(a1, b0, c10, 0, 0, 0);
            c11 = __builtin_amdgcn_mfma_f32_32x32x16_bf16(a1, b1, c11, 0, 0, 0);
        }
    }

    // Write partial G quadrants.  C/D layout (m74/m101).
    float* Gt = Gp + ((size_t)slice * NTRI2 + tile) * 16384;
    const int crow = chsel * 4;
    const int ccol = lane & 31;
    #pragma unroll
    for (int rr = 0; rr < 16; ++rr) {
        const int rl = (rr & 3) + 8*(rr >> 2) + crow;    // 0..31
        const int r0 = qr + rl,  r1 = qr + 32 + rl;
        const int cA = qc + ccol, cB = qc + 32 + ccol;
        Gt[r0*128 + cA] = c00[rr];
        Gt[r0*128 + cB] = c01[rr];
        Gt[r1*128 + cA] = c10[rr];
        Gt[r1*128 + cB] = c11[rr];
    }
}

// ---------------------------------------------------------------------------
// Kernel 2b: sum the 8 K-slice partials, square, weight, reduce.
// 544 blocks, each a quarter-tile (4096 elements), 8 strided reads/elem.
// ---------------------------------------------------------------------------
__global__ __launch_bounds__(256) void gram_reduce(const float* __restrict__ Gp,
                                                   const int* __restrict__ labels,
                                                   double* __restrict__ part1,
                                                   double* __restrict__ part2)
{
    __shared__ float la[128], lb[128];
    __shared__ double red[256];
    const int tid  = threadIdx.x;
    const int tile = blockIdx.x >> 2;
    const int quar = blockIdx.x & 3;
    int bi, bj; tri_decode(tile, bi, bj);

    if (tid < 128) la[tid]       = 2.0f*(float)labels[bi*128 + tid]       - 1.0f;
    else           lb[tid - 128] = 2.0f*(float)labels[bj*128 + tid - 128] - 1.0f;
    __syncthreads();

    const size_t stride = (size_t)NTRI2 * 16384;
    const float* g0 = Gp + (size_t)tile * 16384 + quar * 4096;

    double s1 = 0.0, s2 = 0.0;
    #pragma unroll 2
    for (int u = 0; u < 16; ++u) {
        const int e  = u*256 + tid;          // 0..4095 within quarter
        const int ge = quar*4096 + e;
        float g = 0.f;
        #pragma unroll
        for (int s = 0; s < NSLICE; ++s) g += g0[e + (size_t)s*stride];
        const int row = ge >> 7, col = ge & 127;
        const float w = (bi < bj) ? 2.0f : ((row < col) ? 2.0f : ((row == col) ? 1.0f : 0.0f));
        const float g2 = g * g;
        s1 += (double)(w * la[row] * lb[col] * g2);
        const double d = (double)g2;
        s2 += (double)w * d * d;
    }

    red[tid] = s1; __syncthreads();
    for (int off = 128; off; off >>= 1) { if (tid < off) red[tid] += red[tid+off]; __syncthreads(); }
    if (tid == 0) part1[blockIdx.x] = red[0];
    __syncthreads();
    red[tid] = s2; __syncthreads();
    for (int off = 128; off; off >>= 1) { if (tid < off) red[tid] += red[tid+off]; __syncthreads(); }
    if (tid == 0) part2[blockIdx.x] = red[0];
}

// ---------------------------------------------------------------------------
// Kernel 3: reduce 544 partial slots -> scalar f32.
// square_sum_l = N^2 exactly, so out = s1 / (N * sqrt(s2)).
// ---------------------------------------------------------------------------
__global__ __launch_bounds__(256) void finalize_kernel(const double* __restrict__ part1,
                                                       const double* __restrict__ part2,
                                                       float* __restrict__ out)
{
    __shared__ double r1[256], r2[256];
    const int tid = threadIdx.x;
    double a = 0.0, b = 0.0;
    #pragma unroll
    for (int u = 0; u < 3; ++u) {
        const int s = tid + u*256;
        if (s < NTRI2*4) { a += part1[s]; b += part2[s]; }
    }
    r1[tid] = a; r2[tid] = b; __syncthreads();
    for (int off = 128; off; off >>= 1) {
        if (tid < off) { r1[tid] += r1[tid+off]; r2[tid] += r2[tid+off]; }
        __syncthreads();
    }
    if (tid == 0) out[0] = (float)(r1[0] / (sqrt(r2[0]) * (double)NSAMP));
}

// ---------------------------------------------------------------------------
extern "C" void kernel_launch(void* const* d_in, const int* in_sizes, int n_in,
                              void* d_out, int out_size, void* d_ws, size_t ws_size,
                              hipStream_t stream)
{
    const float* data   = (const float*)d_in[0]; // (2048,12) f32
    const int*   labels = (const int*)d_in[1];   // (2048,)   i32
    const float* params = (const float*)d_in[2]; // (3,12)    f32

    double* part1 = (double*)d_ws;                                    // 544 (pad 768) doubles
    double* part2 = part1 + 768;                                      // 544 doubles
    unsigned short* psi_ext = (unsigned short*)((char*)d_ws + 16384); // 32 MiB
    float* Gp = (float*)((char*)d_ws + 16384 + (size_t)NSAMP*K_EXT*2);// 8x136x16384 f32 = 71.3 MiB

    sim_kernel<<<NSAMP/2, 256, 0, stream>>>(data, params, psi_ext);
    gram_partial<<<NTRI2*NSLICE, 256, 0, stream>>>(psi_ext, Gp);
    gram_reduce<<<NTRI2*4, 256, 0, stream>>>(Gp, labels, part1, part2);
    finalize_kernel<<<1, 256, 0, stream>>>(part1, part2, (float*)d_out);
}

// Round 19
// 147.274 us; speedup vs baseline: 2.5693x; 1.0516x over previous
//
#include <hip/hip_runtime.h>
#include <math.h>

#define NQ    12
#define DIM   4096        // 2^NQ
#define K_EXT 8192        // [hi | lo] extended row
#define KSL   1024        // K per slice (8 slices)
#define NSAMP 2048
#define NLAY  3
#define NT2   16          // 2048/128 tiles per dimension
#define NTRI2 136         // NT2*(NT2+1)/2 triangular tiles
#define NSLICE 8
#define BK    64

typedef __attribute__((ext_vector_type(8)))  short bf16x8;   // 8 bf16 = 4 VGPRs
typedef __attribute__((ext_vector_type(16))) float floatx16; // MFMA 32x32 acc

__device__ __forceinline__ unsigned short f32_to_bf16(float x) {
    unsigned u = __builtin_bit_cast(unsigned, x);
    u += 0x7FFFu + ((u >> 16) & 1u);            // round-to-nearest-even
    return (unsigned short)(u >> 16);
}
__device__ __forceinline__ float bf16_to_f32(unsigned short h) {
    unsigned u = (unsigned)h << 16;
    return __builtin_bit_cast(float, u);
}

// async global->LDS, 16 B per lane; LDS dest = wave-uniform base + lane*16
__device__ __forceinline__ void gl_lds16(const unsigned short* g, unsigned short* l) {
    __builtin_amdgcn_global_load_lds(
        (const __attribute__((address_space(1))) unsigned int*)g,
        (__attribute__((address_space(3))) unsigned int*)l,
        16, 0, 0);
}

__device__ __forceinline__ void tri_decode(int bid, int& bi, int& bj) {
    int i = (int)((33.0 - sqrt(33.0*33.0 - 8.0*(double)bid)) * 0.5);
    int start = i*(33-i)/2;
    while (bid < start)               { --i; start = i*(33-i)/2; }
    while (bid >= start + (NT2 - i))  { start += NT2 - i; ++i; }
    bi = i; bj = i + (bid - start);
}

// ---------------------------------------------------------------------------
// Kernel 1: TRANSPOSE-BASED simulator — zero ds_bpermute (sim was LDS-pipe
// bound on 384 bpermutes/wave).  One sample per two waves, v[32]/lane.
// Map0: amp i held at (lane=i0..i5, w=i6, r=i7..i11).
// Map1: amp i held at (l'0,l'1=i0,i1; r'=i2..i6; l'2..l'5=i7..i10; w'=i11).
// Each layer: 5 reg butterflies + 2 DPP (lane bits 0,1) + ONE LDS transpose
// (8 ds_write_b128 + 32 ds_read_b32) + 5 more reg butterflies + CZ sign.
// CZ parity computed exactly from the reconstructed 12-bit index.
// Final state in Map1; store order is a fixed sample-independent k-perm
// (Gram-invariant).  Chunk-swizzle for gram's global_load_lds kept.
// ---------------------------------------------------------------------------
__global__ __launch_bounds__(256) void sim_kernel(const float* __restrict__ data,
                                                  const float* __restrict__ params,
                                                  unsigned short* __restrict__ pe)
{
    __shared__ float CS[2*36], SN[2*36];
    __shared__ float trans[2][4608];    // padded transpose buffer (18 KiB/sample)
    const int tid  = threadIdx.x;
    const int wave = tid >> 6, lane = tid & 63;
    const int sidx = wave >> 1;         // sample within block
    const int w    = wave & 1;
    const int smp  = blockIdx.x * 2 + sidx;

    if (w == 0 && lane < NLAY*NQ) {
        const int q = lane % NQ;
        const float th = 0.5f * (params[lane] + data[smp*NQ + q]);
        CS[sidx*36 + lane] = cosf(th);
        SN[sidx*36 + lane] = sinf(th);
    }
    __syncthreads();

    float v[32];
    #pragma unroll
    for (int r = 0; r < 32; ++r) v[r] = 0.f;
    if (w == 0 && lane == 0) v[0] = 1.f;   // Map0 amp 0

    float* buf = trans[sidx];
    float* wb  = buf + 36*lane + 2304*w;                         // writer base
    const float* rb = buf + ((lane>>2)&15) + 16*w + 36*(lane&3); // reader base

    #pragma unroll 1
    for (int l = 0; l < NLAY; ++l) {
        const float* cs = &CS[sidx*36 + l*NQ];
        const float* sn = &SN[sidx*36 + l*NQ];
        const int even = !(l & 1);       // even: state in Map0, else Map1

        // ---- first 5 register butterflies (q7-11 in Map0, q2-6 in Map1) ----
        {
            const int qb = even ? 7 : 2;
            #pragma unroll
            for (int b = 0; b < 5; ++b) {
                const float c = cs[qb + b], s = sn[qb + b];
                const int M = 1 << b;
                #pragma unroll
                for (int r = 0; r < 32; ++r) {
                    if (!(r & M)) {
                        const float a0 = v[r], a1 = v[r | M];
                        v[r]     = c * a0 - s * a1;
                        v[r | M] = s * a0 + c * a1;
                    }
                }
            }
        }
        // ---- qubits 0,1 (lane bits 0,1 in both maps): DPP quad_perm ----
        {
            const float c0 = cs[0], s0 = sn[0];
            const float t0 = (lane & 1) ? s0 : -s0;
            #pragma unroll
            for (int r = 0; r < 32; ++r) {
                const int iv = __builtin_bit_cast(int, v[r]);
                const int pv = __builtin_amdgcn_update_dpp(0, iv, 0xB1, 0xF, 0xF, true);
                v[r] = c0 * v[r] + t0 * __builtin_bit_cast(float, pv);
            }
            const float c1 = cs[1], s1 = sn[1];
            const float t1 = (lane & 2) ? s1 : -s1;
            #pragma unroll
            for (int r = 0; r < 32; ++r) {
                const int iv = __builtin_bit_cast(int, v[r]);
                const int pv = __builtin_amdgcn_update_dpp(0, iv, 0x4E, 0xF, 0xF, true);
                v[r] = c1 * v[r] + t1 * __builtin_bit_cast(float, pv);
            }
        }
        // ---- transpose: swap (lane bits 2-5, w) <-> register bits ----
        __syncthreads();                 // prior reads of buf complete
        #pragma unroll
        for (int t = 0; t < 8; ++t) {
            float4 q4;
            q4.x = v[4*t]; q4.y = v[4*t+1]; q4.z = v[4*t+2]; q4.w = v[4*t+3];
            *(float4*)&wb[4*t] = q4;
        }
        __syncthreads();
        #pragma unroll
        for (int r = 0; r < 32; ++r)
            v[r] = rb[144*(r & 15) + 2304*(r >> 4)];

        // ---- second 5 register butterflies (q2-6 if even, q7-11 if odd) ----
        {
            const int qb = even ? 2 : 7;
            #pragma unroll
            for (int b = 0; b < 5; ++b) {
                const float c = cs[qb + b], s = sn[qb + b];
                const int M = 1 << b;
                #pragma unroll
                for (int r = 0; r < 32; ++r) {
                    if (!(r & M)) {
                        const float a0 = v[r], a1 = v[r | M];
                        v[r]     = c * a0 - s * a1;
                        v[r | M] = s * a0 + c * a1;
                    }
                }
            }
        }
        // ---- CZ ring sign: exact parity from reconstructed index ----
        // after even layer: state in Map1: i = (lane&3)|(r<<2)|(((lane>>2)&15)<<7)|(w<<11)
        // after odd  layer: state in Map0: i = lane|(w<<6)|(r<<7)
        {
            const int Base = even ? ((lane & 3) | (((lane >> 2) & 15) << 7) | (w << 11))
                                  : (lane | (w << 6));
            const int shift = even ? 2 : 7;
            #pragma unroll
            for (int r = 0; r < 32; ++r) {
                const int i  = Base | (r << shift);
                const int t  = ((i >> 1) | (i << 11)) & 0xFFF;
                const int p  = __popc(i & t) & 1;
                v[r] = __builtin_bit_cast(float, __builtin_bit_cast(int, v[r]) ^ (p << 31));
            }
        }
    }

    // state ends in Map1 (3 layers).  k = (w*64+lane)*32 + r — a fixed
    // sample-independent permutation -> Gram-invariant.
    const int sw = smp & 7;
    const int ell = w*64 + lane;
    unsigned short* outb = pe + (size_t)smp * K_EXT;
    #pragma unroll
    for (int c = 0; c < 4; ++c) {
        uint4 H, L;
        {
            const float x0 = v[c*8+0], x1 = v[c*8+1];
            const unsigned short h0 = f32_to_bf16(x0), h1 = f32_to_bf16(x1);
            H.x = (unsigned)h0 | ((unsigned)h1 << 16);
            L.x = (unsigned)f32_to_bf16(x0 - bf16_to_f32(h0)) |
                  ((unsigned)f32_to_bf16(x1 - bf16_to_f32(h1)) << 16);
        }
        {
            const float x0 = v[c*8+2], x1 = v[c*8+3];
            const unsigned short h0 = f32_to_bf16(x0), h1 = f32_to_bf16(x1);
            H.y = (unsigned)h0 | ((unsigned)h1 << 16);
            L.y = (unsigned)f32_to_bf16(x0 - bf16_to_f32(h0)) |
                  ((unsigned)f32_to_bf16(x1 - bf16_to_f32(h1)) << 16);
        }
        {
            const float x0 = v[c*8+4], x1 = v[c*8+5];
            const unsigned short h0 = f32_to_bf16(x0), h1 = f32_to_bf16(x1);
            H.z = (unsigned)h0 | ((unsigned)h1 << 16);
            L.z = (unsigned)f32_to_bf16(x0 - bf16_to_f32(h0)) |
                  ((unsigned)f32_to_bf16(x1 - bf16_to_f32(h1)) << 16);
        }
        {
            const float x0 = v[c*8+6], x1 = v[c*8+7];
            const unsigned short h0 = f32_to_bf16(x0), h1 = f32_to_bf16(x1);
            H.w = (unsigned)h0 | ((unsigned)h1 << 16);
            L.w = (unsigned)f32_to_bf16(x0 - bf16_to_f32(h0)) |
                  ((unsigned)f32_to_bf16(x1 - bf16_to_f32(h1)) << 16);
        }
        const int gc  = 4*ell + c;
        const int pos = (gc & ~7) | ((gc ^ sw) & 7);
        *(uint4*)&outb[pos*8]       = H;
        *(uint4*)&outb[DIM + pos*8] = L;
    }
}

// ---------------------------------------------------------------------------
// Kernel 2a (unchanged from R18): partial Gram with async global_load_lds
// staging; psi chunk-swizzled in global -> packed LDS (LDK=64) stays near
// conflict-free.  1088 blocks = 136 tiles x 8 K-slices, tile-major decode
// (one K-slice per XCD = 4 MiB = its L2; FETCH 24 MB verified).
// ---------------------------------------------------------------------------
__global__ __launch_bounds__(256) void gram_partial(const unsigned short* __restrict__ pe,
                                                    float* __restrict__ Gp)
{
    __shared__ __align__(16) unsigned short stage[2*128*64];   // A|B, 32 KiB

    unsigned short* As = stage;
    unsigned short* Bs = stage + 128*64;

    const int tid   = threadIdx.x;
    const int tile  = blockIdx.x >> 3;     // bi-major tile walk per XCD
    const int slice = blockIdx.x & 7;      // one K-slice per XCD (bid % 8)
    int bi, bj; tri_decode(tile, bi, bj);
    const int k0 = slice * KSL;

    const int wave = tid >> 6, lane = tid & 63;
    const int qr = (wave >> 1) * 64;   // quadrant row offset
    const int qc = (wave &  1) * 64;   // quadrant col offset
    const int mrow = lane & 31;
    const int chsel = lane >> 5;       // chunk half-select within 16-k group
    const int sw = mrow & 7;           // read-side swizzle key (= row&7)

    floatx16 c00, c01, c10, c11;
    #pragma unroll
    for (int i = 0; i < 16; ++i) { c00[i]=0.f; c01[i]=0.f; c10[i]=0.f; c11[i]=0.f; }

    const int mat  = wave >> 1;            // 0=A, 1=B
    const int half = wave & 1;
    const unsigned short* gbase = pe
        + ((size_t)((mat ? bj : bi)*128 + half*64 + (lane >> 3))) * K_EXT
        + k0 + (lane & 7)*8;
    unsigned short* lbase = (mat ? Bs : As) + half*64*64;   // ushort units

    for (int kk = 0; kk < KSL; kk += BK) {
        __syncthreads();                       // prev compute done; LDS free
        const unsigned short* g = gbase + kk;
        #pragma unroll
        for (int i = 0; i < 8; ++i)
            gl_lds16(g + (size_t)i*8*K_EXT, lbase + i*512);
        __syncthreads();                       // drains vmcnt -> LDS visible

        #pragma unroll
        for (int ks = 0; ks < 4; ++ks) {
            const int ch = (ks*2 + chsel) ^ sw;            // swizzled chunk
            const bf16x8 a0 = *(const bf16x8*)&As[(qr +      mrow)*64 + ch*8];
            const bf16x8 a1 = *(const bf16x8*)&As[(qr + 32 + mrow)*64 + ch*8];
            const bf16x8 b0 = *(const bf16x8*)&Bs[(qc +      mrow)*64 + ch*8];
            const bf16x8 b1 = *(const bf16x8*)&Bs[(qc + 32 + mrow)*64 + ch*8];
            c00 = __builtin_amdgcn_mfma_f32_32x32x16_bf16(a0, b0, c00, 0, 0, 0);
            c01 = __builtin_amdgcn_mfma_f32_32x32x16_bf16(a0, b1, c01, 0, 0, 0);
            c10 = __builtin_amdgcn_mfma_f32_32x32x16_bf16(a1, b0, c10, 0, 0, 0);
            c11 = __builtin_amdgcn_mfma_f32_32x32x16_bf16(a1, b1, c11, 0, 0, 0);
        }
    }

    // Write partial G quadrants.  C/D layout (m74/m101).
    float* Gt = Gp + ((size_t)slice * NTRI2 + tile) * 16384;
    const int crow = chsel * 4;
    const int ccol = lane & 31;
    #pragma unroll
    for (int rr = 0; rr < 16; ++rr) {
        const int rl = (rr & 3) + 8*(rr >> 2) + crow;    // 0..31
        const int r0 = qr + rl,  r1 = qr + 32 + rl;
        const int cA = qc + ccol, cB = qc + 32 + ccol;
        Gt[r0*128 + cA] = c00[rr];
        Gt[r0*128 + cB] = c01[rr];
        Gt[r1*128 + cA] = c10[rr];
        Gt[r1*128 + cB] = c11[rr];
    }
}

// ---------------------------------------------------------------------------
// Kernel 2b: sum the 8 K-slice partials, square, weight, reduce.
// 544 blocks, each a quarter-tile (4096 elements), 8 strided reads/elem.
// ---------------------------------------------------------------------------
__global__ __launch_bounds__(256) void gram_reduce(const float* __restrict__ Gp,
                                                   const int* __restrict__ labels,
                                                   double* __restrict__ part1,
                                                   double* __restrict__ part2)
{
    __shared__ float la[128], lb[128];
    __shared__ double red[256];
    const int tid  = threadIdx.x;
    const int tile = blockIdx.x >> 2;
    const int quar = blockIdx.x & 3;
    int bi, bj; tri_decode(tile, bi, bj);

    if (tid < 128) la[tid]       = 2.0f*(float)labels[bi*128 + tid]       - 1.0f;
    else           lb[tid - 128] = 2.0f*(float)labels[bj*128 + tid - 128] - 1.0f;
    __syncthreads();

    const size_t stride = (size_t)NTRI2 * 16384;
    const float* g0 = Gp + (size_t)tile * 16384 + quar * 4096;

    double s1 = 0.0, s2 = 0.0;
    #pragma unroll 2
    for (int u = 0; u < 16; ++u) {
        const int e  = u*256 + tid;          // 0..4095 within quarter
        const int ge = quar*4096 + e;
        float g = 0.f;
        #pragma unroll
        for (int s = 0; s < NSLICE; ++s) g += g0[e + (size_t)s*stride];
        const int row = ge >> 7, col = ge & 127;
        const float w = (bi < bj) ? 2.0f : ((row < col) ? 2.0f : ((row == col) ? 1.0f : 0.0f));
        const float g2 = g * g;
        s1 += (double)(w * la[row] * lb[col] * g2);
        const double d = (double)g2;
        s2 += (double)w * d * d;
    }

    red[tid] = s1; __syncthreads();
    for (int off = 128; off; off >>= 1) { if (tid < off) red[tid] += red[tid+off]; __syncthreads(); }
    if (tid == 0) part1[blockIdx.x] = red[0];
    __syncthreads();
    red[tid] = s2; __syncthreads();
    for (int off = 128; off; off >>= 1) { if (tid < off) red[tid] += red[tid+off]; __syncthreads(); }
    if (tid == 0) part2[blockIdx.x] = red[0];
}

// ---------------------------------------------------------------------------
// Kernel 3: reduce 544 partial slots -> scalar f32.
// square_sum_l = N^2 exactly, so out = s1 / (N * sqrt(s2)).
// ---------------------------------------------------------------------------
__global__ __launch_bounds__(256) void finalize_kernel(const double* __restrict__ part1,
                                                       const double* __restrict__ part2,
                                                       float* __restrict__ out)
{
    __shared__ double r1[256], r2[256];
    const int tid = threadIdx.x;
    double a = 0.0, b = 0.0;
    #pragma unroll
    for (int u = 0; u < 3; ++u) {
        const int s = tid + u*256;
        if (s < NTRI2*4) { a += part1[s]; b += part2[s]; }
    }
    r1[tid] = a; r2[tid] = b; __syncthreads();
    for (int off = 128; off; off >>= 1) {
        if (tid < off) { r1[tid] += r1[tid+off]; r2[tid] += r2[tid+off]; }
        __syncthreads();
    }
    if (tid == 0) out[0] = (float)(r1[0] / (sqrt(r2[0]) * (double)NSAMP));
}

// ---------------------------------------------------------------------------
extern "C" void kernel_launch(void* const* d_in, const int* in_sizes, int n_in,
                              void* d_out, int out_size, void* d_ws, size_t ws_size,
                              hipStream_t stream)
{
    const float* data   = (const float*)d_in[0]; // (2048,12) f32
    const int*   labels = (const int*)d_in[1];   // (2048,)   i32
    const float* params = (const float*)d_in[2]; // (3,12)    f32

    double* part1 = (double*)d_ws;                                    // 544 (pad 768) doubles
    double* part2 = part1 + 768;                                      // 544 doubles
    unsigned short* psi_ext = (unsigned short*)((char*)d_ws + 16384); // 32 MiB
    float* Gp = (float*)((char*)d_ws + 16384 + (size_t)NSAMP*K_EXT*2);// 8x136x16384 f32 = 71.3 MiB

    sim_kernel<<<NSAMP/2, 256, 0, stream>>>(data, params, psi_ext);
    gram_partial<<<NTRI2*NSLICE, 256, 0, stream>>>(psi_ext, Gp);
    gram_reduce<<<NTRI2*4, 256, 0, stream>>>(Gp, labels, part1, part2);
    finalize_kernel<<<1, 256, 0, stream>>>(part1, part2, (float*)d_out);
}